// Round 9
// baseline (910.762 us; speedup 1.0000x reference)
//
#include <hip/hip_runtime.h>
#include <hip/hip_bf16.h>
#include <hip/hip_fp16.h>

typedef _Float16 half8 __attribute__((ext_vector_type(8)));
typedef _Float16 half4v __attribute__((ext_vector_type(4)));
typedef float f32x4 __attribute__((ext_vector_type(4)));

#define T_DIM 196
#define B_DIM 64
#define C_DIM 1024
#define E_DIM 512
#define CE (C_DIM * E_DIM)   // 524288
#define LN_EPS 1e-5f

// ws layout (bytes)
#define META_OFF 0            // ints: [0]=ucount, [1..64]=inv[b], [65..128]=utoks
#define H_OFF 4096            // 64 * 512 f32 = 131072
#define FEATN_OFF 135168      // T*B*C f16 = 25690112 (layout [b][T][C])
#define WMAP_OFF 25825280     // cap * CE f16 (1 MiB per slot, cap<=64)
#define PROBE_OFF (WMAP_OFF + 67108864)   // past the 64-slot wmap region

// ---------------------------------------------------------------- dedupe
__global__ void k_prep(const int* __restrict__ toks, int* __restrict__ meta) {
    __shared__ int st[B_DIM];
    int tid = threadIdx.x;
    if (tid < B_DIM) st[tid] = toks[tid];
    __syncthreads();
    if (tid == 0) {
        int ut[B_DIM];
        int inv[B_DIM];
        int ucount = 0;
        for (int b = 0; b < B_DIM; ++b) {
            int t = st[b];
            int slot = -1;
            for (int j = 0; j < ucount; ++j)
                if (ut[j] == t) { slot = j; break; }
            if (slot < 0) { slot = ucount; ut[ucount++] = t; }
            inv[b] = slot;
        }
        meta[0] = ucount;
        for (int b = 0; b < B_DIM; ++b) meta[1 + b] = inv[b];
        for (int j = 0; j < B_DIM; ++j) meta[65 + j] = (j < ucount) ? ut[j] : 0;
    }
}

// ------------------------------------------------- embed LN + h = relu(ln @ W1^T + b1)
__global__ __launch_bounds__(256) void k_gen_h(
        const float* __restrict__ embed_table, const float* __restrict__ g,
        const float* __restrict__ bb, const float* __restrict__ W1,
        const float* __restrict__ b1, const int* __restrict__ meta,
        float* __restrict__ h) {
    int u = blockIdx.x;
    int ucount = meta[0];
    int tid = threadIdx.x;
    if (u >= ucount) {
        h[(size_t)u * E_DIM + tid] = 0.0f;
        h[(size_t)u * E_DIM + tid + 256] = 0.0f;
        return;
    }
    int tok = meta[65 + u];
    const float* row = embed_table + (size_t)tok * E_DIM;
    float x0 = row[tid], x1 = row[tid + 256];
    float s = x0 + x1, sq = x0 * x0 + x1 * x1;
    #pragma unroll
    for (int m = 1; m < 64; m <<= 1) { s += __shfl_xor(s, m, 64); sq += __shfl_xor(sq, m, 64); }
    __shared__ float red[4][2];
    int wv = tid >> 6, ln = tid & 63;
    if (ln == 0) { red[wv][0] = s; red[wv][1] = sq; }
    __syncthreads();
    s = red[0][0] + red[1][0] + red[2][0] + red[3][0];
    sq = red[0][1] + red[1][1] + red[2][1] + red[3][1];
    float mu = s * (1.0f / E_DIM);
    float rs = rsqrtf(sq * (1.0f / E_DIM) - mu * mu + LN_EPS);
    __shared__ float lnv[E_DIM];
    lnv[tid] = (x0 - mu) * rs * g[tid] + bb[tid];
    lnv[tid + 256] = (x1 - mu) * rs * g[tid + 256] + bb[tid + 256];
    __syncthreads();
    #pragma unroll
    for (int cc = 0; cc < 2; ++cc) {
        int col = tid + cc * 256;
        const float* wrow = W1 + (size_t)col * E_DIM;
        float acc = b1[col];
        for (int k = 0; k < E_DIM; k += 4) {
            float4 w = *(const float4*)(wrow + k);
            float4 l4 = *(const float4*)(&lnv[k]);
            acc += w.x * l4.x + w.y * l4.y + w.z * l4.z + w.w * l4.w;
        }
        h[(size_t)u * E_DIM + col] = fmaxf(acc, 0.0f);
    }
}

// ------------------------------------------------- feat LN -> f16, layout [b][T][C]
__global__ __launch_bounds__(256) void k_featn(
        const float* __restrict__ feat, const float* __restrict__ g,
        const float* __restrict__ bb, _Float16* __restrict__ featn) {
    int r = blockIdx.x;              // r = t*B + b (source row, LN over contiguous C)
    int t = r / B_DIM, b = r % B_DIM;
    const float* x = feat + (size_t)r * C_DIM;
    int tid = threadIdx.x;
    float4 v = *(const float4*)(x + tid * 4);
    float s = v.x + v.y + v.z + v.w;
    float sq = v.x * v.x + v.y * v.y + v.z * v.z + v.w * v.w;
    #pragma unroll
    for (int m = 1; m < 64; m <<= 1) { s += __shfl_xor(s, m, 64); sq += __shfl_xor(sq, m, 64); }
    __shared__ float red[4][2];
    int wv = tid >> 6, ln = tid & 63;
    if (ln == 0) { red[wv][0] = s; red[wv][1] = sq; }
    __syncthreads();
    s = red[0][0] + red[1][0] + red[2][0] + red[3][0];
    sq = red[0][1] + red[1][1] + red[2][1] + red[3][1];
    float mu = s * (1.0f / C_DIM);
    float rs = rsqrtf(sq * (1.0f / C_DIM) - mu * mu + LN_EPS);
    float4 gv = *(const float4*)(g + tid * 4);
    float4 bv = *(const float4*)(bb + tid * 4);
    half4v o;
    o[0] = (_Float16)((v.x - mu) * rs * gv.x + bv.x);
    o[1] = (_Float16)((v.y - mu) * rs * gv.y + bv.y);
    o[2] = (_Float16)((v.z - mu) * rs * gv.z + bv.z);
    o[3] = (_Float16)((v.w - mu) * rs * gv.w + bv.w);
    *(half4v*)(featn + ((size_t)b * T_DIM + t) * C_DIM + tid * 4) = o;
}

// ------------------------------------------------- Wmap via MFMA (round-6 version: best known, 333us total)
__global__ __launch_bounds__(256) void k_wmap(
        const float* __restrict__ W2, const float* __restrict__ b2,
        const float* __restrict__ h, const int* __restrict__ meta,
        _Float16* __restrict__ wmap, int cap) {
    int ucount = meta[0];
    if (ucount > cap) ucount = cap;
    int tid = threadIdx.x;
    int lane = tid & 63;
    int wid = tid >> 6;
    int fr = lane & 15, fq = lane >> 4;
    int l5 = lane >> 5;
    int c31 = lane & 31;
    __shared__ float sbuf[4][2][16][128];   // [wave][buf][row][f32] = 64 KB
    __shared__ _Float16 hseg[16][64][8];    // B-fragments, 16 KB

    long nwaves = (long)gridDim.x * 4;
    long gw = (long)blockIdx.x * 4 + wid;
    const long NT = CE / 16;

    for (int sg = 0; sg < ucount; sg += 16) {
        __syncthreads();
        {
            int pfr = tid & 15, pks = tid >> 4;
            const float* hp = h + (size_t)(sg + pfr) * E_DIM + pks * 32;
            #pragma unroll
            for (int pq = 0; pq < 4; ++pq) {
                float4 a = *(const float4*)(hp + pq * 8);
                float4 b = *(const float4*)(hp + pq * 8 + 4);
                half8 v;
                v[0] = (_Float16)a.x; v[1] = (_Float16)a.y;
                v[2] = (_Float16)a.z; v[3] = (_Float16)a.w;
                v[4] = (_Float16)b.x; v[5] = (_Float16)b.y;
                v[6] = (_Float16)b.z; v[7] = (_Float16)b.w;
                *(half8*)(&hseg[pks][pq * 16 + pfr][0]) = v;
            }
        }
        __syncthreads();
        int nu = ucount - sg;

        long ntiles = (gw < NT) ? ((NT - gw + nwaves - 1) / nwaves) : 0;
        if (ntiles > 0) {
            long nq = ntiles * 4;
            {
                long i0 = gw * 16;
                #pragma unroll
                for (int s = 0; s < 8; ++s) {
                    int row = 2 * s + l5;
                    float4 rv = *(const float4*)(W2 + (size_t)(i0 + row) * E_DIM + c31 * 4);
                    *(float4*)(&sbuf[wid][0][row][(c31 ^ (row & 7)) * 4]) = rv;
                }
            }
            f32x4 acc = {};
            for (long qq = 0; qq < nq; ++qq) {
                int cur = (int)(qq & 1);
                bool have = (qq + 1 < nq);
                float4 rr0, rr1, rr2, rr3, rr4, rr5, rr6, rr7;
                if (have) {
                    long g2 = gw + ((qq + 1) >> 2) * nwaves;
                    int qn = (int)((qq + 1) & 3);
                    const float* base = W2 + (size_t)(g2 * 16) * E_DIM + qn * 128 + c31 * 4;
                    rr0 = *(const float4*)(base + (size_t)(0  + l5) * E_DIM);
                    rr1 = *(const float4*)(base + (size_t)(2  + l5) * E_DIM);
                    rr2 = *(const float4*)(base + (size_t)(4  + l5) * E_DIM);
                    rr3 = *(const float4*)(base + (size_t)(6  + l5) * E_DIM);
                    rr4 = *(const float4*)(base + (size_t)(8  + l5) * E_DIM);
                    rr5 = *(const float4*)(base + (size_t)(10 + l5) * E_DIM);
                    rr6 = *(const float4*)(base + (size_t)(12 + l5) * E_DIM);
                    rr7 = *(const float4*)(base + (size_t)(14 + l5) * E_DIM);
                    __builtin_amdgcn_sched_barrier(0);
                }
                int q = (int)(qq & 3);
                #pragma unroll
                for (int ks = 0; ks < 4; ++ks) {
                    int c0 = ks * 8 + fq * 2;
                    float4 x0 = *(const float4*)(&sbuf[wid][cur][fr][(c0 ^ (fr & 7)) * 4]);
                    float4 x1 = *(const float4*)(&sbuf[wid][cur][fr][((c0 + 1) ^ (fr & 7)) * 4]);
                    half8 af;
                    af[0] = (_Float16)x0.x; af[1] = (_Float16)x0.y;
                    af[2] = (_Float16)x0.z; af[3] = (_Float16)x0.w;
                    af[4] = (_Float16)x1.x; af[5] = (_Float16)x1.y;
                    af[6] = (_Float16)x1.z; af[7] = (_Float16)x1.w;
                    half8 bf = *(const half8*)(&hseg[q * 4 + ks][lane][0]);
                    acc = __builtin_amdgcn_mfma_f32_16x16x32_f16(af, bf, acc, 0, 0, 0);
                }
                if (q == 3) {
                    long i0 = (gw + (qq >> 2) * nwaves) * 16;
                    if (fr < nu) {
                        float4 bv = *(const float4*)(b2 + i0 + fq * 4);
                        half4v o;
                        o[0] = (_Float16)fmaxf(acc[0] + bv.x, 0.0f);
                        o[1] = (_Float16)fmaxf(acc[1] + bv.y, 0.0f);
                        o[2] = (_Float16)fmaxf(acc[2] + bv.z, 0.0f);
                        o[3] = (_Float16)fmaxf(acc[3] + bv.w, 0.0f);
                        *(half4v*)(wmap + (size_t)(sg + fr) * CE + i0 + fq * 4) = o;
                    }
                    acc[0] = 0.0f; acc[1] = 0.0f; acc[2] = 0.0f; acc[3] = 0.0f;
                }
                if (have) {
                    int nb = cur ^ 1;
                    *(float4*)(&sbuf[wid][nb][0  + l5][(c31 ^ ((0  + l5) & 7)) * 4]) = rr0;
                    *(float4*)(&sbuf[wid][nb][2  + l5][(c31 ^ ((2  + l5) & 7)) * 4]) = rr1;
                    *(float4*)(&sbuf[wid][nb][4  + l5][(c31 ^ ((4  + l5) & 7)) * 4]) = rr2;
                    *(float4*)(&sbuf[wid][nb][6  + l5][(c31 ^ ((6  + l5) & 7)) * 4]) = rr3;
                    *(float4*)(&sbuf[wid][nb][8  + l5][(c31 ^ ((8  + l5) & 7)) * 4]) = rr4;
                    *(float4*)(&sbuf[wid][nb][10 + l5][(c31 ^ ((10 + l5) & 7)) * 4]) = rr5;
                    *(float4*)(&sbuf[wid][nb][12 + l5][(c31 ^ ((12 + l5) & 7)) * 4]) = rr6;
                    *(float4*)(&sbuf[wid][nb][14 + l5][(c31 ^ ((14 + l5) & 7)) * 4]) = rr7;
                }
            }
        }
    }
}

// ------------------------------------------------- out = featn @ Wmap[inv[b]]^T (per batch)
__global__ __launch_bounds__(256) void k_einsum(
        const _Float16* __restrict__ featn, const _Float16* __restrict__ wmap,
        const int* __restrict__ meta, float* __restrict__ out, int cap) {
    int b = blockIdx.z;
    int s = meta[1 + b];
    if (s >= cap) s = cap - 1;
    int M0 = blockIdx.y * 128;
    int N0 = blockIdx.x * 128;
    __shared__ _Float16 As[4][128][8];
    __shared__ _Float16 Bs[4][128][8];
    const _Float16* Abase = featn + (size_t)b * T_DIM * C_DIM;
    const _Float16* Bbase = wmap + (size_t)s * CE + (size_t)N0 * C_DIM;
    int tid = threadIdx.x;
    int lane = tid & 63, wv = tid >> 6;
    int wrow = (wv >> 1) * 64, wcol = (wv & 1) * 64;
    int fr = lane & 15, fq = lane >> 4;
    f32x4 acc[4][4] = {};
    for (int kt = 0; kt < C_DIM / 32; ++kt) {
        int k0 = kt * 32;
        #pragma unroll
        for (int hh = 0; hh < 2; ++hh) {
            int id = tid + hh * 256;
            int r = id >> 2, q = id & 3;
            int t = M0 + r;
            uint4 av = make_uint4(0u, 0u, 0u, 0u);
            if (t < T_DIM) av = *(const uint4*)(Abase + (size_t)t * C_DIM + k0 + q * 8);
            *(uint4*)(&As[q][r][0]) = av;
            uint4 bvv = *(const uint4*)(Bbase + (size_t)r * C_DIM + k0 + q * 8);
            *(uint4*)(&Bs[q][r][0]) = bvv;
        }
        __syncthreads();
        half8 af[4], bf[4];
        #pragma unroll
        for (int mi = 0; mi < 4; ++mi) af[mi] = *(const half8*)(&As[fq][wrow + mi * 16 + fr][0]);
        #pragma unroll
        for (int ni = 0; ni < 4; ++ni) bf[ni] = *(const half8*)(&Bs[fq][wcol + ni * 16 + fr][0]);
        #pragma unroll
        for (int mi = 0; mi < 4; ++mi) {
            #pragma unroll
            for (int ni = 0; ni < 4; ++ni) {
                acc[mi][ni] = __builtin_amdgcn_mfma_f32_16x16x32_f16(af[mi], bf[ni], acc[mi][ni], 0, 0, 0);
            }
        }
        __syncthreads();
    }
    #pragma unroll
    for (int mi = 0; mi < 4; ++mi) {
        #pragma unroll
        for (int ni = 0; ni < 4; ++ni) {
            #pragma unroll
            for (int j = 0; j < 4; ++j) {
                int t = M0 + wrow + mi * 16 + fq * 4 + j;
                int e = N0 + wcol + ni * 16 + fr;
                if (t < T_DIM)
                    out[((size_t)t * B_DIM + b) * E_DIM + e] = acc[mi][ni][j];
            }
        }
    }
}

// ------------------------------------------------- DIAGNOSTIC: pure-read BW probe
// Measures the chip's read-only streaming ceiling on the exact W2 buffer: canonical
// grid-stride float4 sweep x3 (3.22 GB total so the dispatch outranks the ~700us
// harness fills and surfaces in the rocprof top-5). Accumulate + tail write to dead
// ws space prevents DCE. Deterministic; removed next round.
__global__ __launch_bounds__(256) void k_probe(const float* __restrict__ W2,
                                               float4* __restrict__ outp) {
    long tid = (long)blockIdx.x * 256 + threadIdx.x;
    long nthr = (long)gridDim.x * 256;
    const float4* p = (const float4*)W2;
    const long n4 = (long)CE * E_DIM / 4;   // 67,108,864 float4 = 1.07 GB
    float4 acc = make_float4(0.f, 0.f, 0.f, 0.f);
    for (int rep = 0; rep < 3; ++rep) {
        #pragma unroll 4
        for (long i = tid; i < n4; i += nthr) {
            float4 v = p[i];
            acc.x += v.x; acc.y += v.y; acc.z += v.z; acc.w += v.w;
        }
    }
    outp[tid] = acc;
}

extern "C" void kernel_launch(void* const* d_in, const int* in_sizes, int n_in,
                              void* d_out, int out_size, void* d_ws, size_t ws_size,
                              hipStream_t stream) {
    const float* feat = (const float*)d_in[0];
    const int* toks = (const int*)d_in[1];
    const float* embed_table = (const float*)d_in[2];
    const float* eg = (const float*)d_in[3];
    const float* ebv = (const float*)d_in[4];
    const float* fg = (const float*)d_in[5];
    const float* fb = (const float*)d_in[6];
    const float* W1 = (const float*)d_in[7];
    const float* b1 = (const float*)d_in[8];
    const float* W2 = (const float*)d_in[9];
    const float* b2 = (const float*)d_in[10];
    float* out = (float*)d_out;

    char* ws = (char*)d_ws;
    int* meta = (int*)(ws + META_OFF);
    float* h = (float*)(ws + H_OFF);
    _Float16* featn = (_Float16*)(ws + FEATN_OFF);
    _Float16* wmap = (_Float16*)(ws + WMAP_OFF);
    float4* probeout = (float4*)(ws + PROBE_OFF);

    long cap = 1;
    if (ws_size > (size_t)WMAP_OFF)
        cap = (long)((ws_size - (size_t)WMAP_OFF) / ((size_t)CE * 2));
    if (cap > 64) cap = 64;
    if (cap < 1) cap = 1;

    hipLaunchKernelGGL(k_prep, dim3(1), dim3(64), 0, stream, toks, meta);
    hipLaunchKernelGGL(k_gen_h, dim3(64), dim3(256), 0, stream,
                       embed_table, eg, ebv, W1, b1, meta, h);
    hipLaunchKernelGGL(k_featn, dim3(T_DIM * B_DIM), dim3(256), 0, stream,
                       feat, fg, fb, featn);
    hipLaunchKernelGGL(k_wmap, dim3(1024), dim3(256), 0, stream,
                       W2, b2, h, meta, wmap, (int)cap);
    hipLaunchKernelGGL(k_einsum, dim3(4, 2, 64), dim3(256), 0, stream,
                       featn, wmap, meta, out, (int)cap);
    // DIAGNOSTIC (this round only): pure-read ceiling probe, launched last.
    if (ws_size >= (size_t)PROBE_OFF + (size_t)2048 * 256 * 16)
        hipLaunchKernelGGL(k_probe, dim3(2048), dim3(256), 0, stream, W2, probeout);
}

// Round 10
// 405.771 us; speedup vs baseline: 2.2445x; 2.2445x over previous
//
#include <hip/hip_runtime.h>
#include <hip/hip_bf16.h>
#include <hip/hip_fp16.h>

typedef _Float16 half8 __attribute__((ext_vector_type(8)));
typedef _Float16 half4v __attribute__((ext_vector_type(4)));
typedef float f32x4 __attribute__((ext_vector_type(4)));

#define T_DIM 196
#define B_DIM 64
#define C_DIM 1024
#define E_DIM 512
#define CE (C_DIM * E_DIM)   // 524288
#define LN_EPS 1e-5f

// ws layout (bytes)
#define META_OFF 0            // ints: [0]=ucount, [1..64]=inv[b], [65..128]=utoks
#define H_OFF 4096            // 64 * 512 f32 = 131072
#define FEATN_OFF 135168      // T*B*C f16 = 25690112 (layout [b][T][C])
#define WMAP_OFF 25825280     // cap * CE f16 (1 MiB per slot, cap<=64)

#define WAITV(N) do { asm volatile("s_waitcnt vmcnt(" #N ")" ::: "memory"); \
                      __builtin_amdgcn_sched_barrier(0); } while (0)
#define WAITL()  do { asm volatile("s_waitcnt lgkmcnt(0)" ::: "memory"); \
                      __builtin_amdgcn_sched_barrier(0); } while (0)

// ---------------------------------------------------------------- dedupe
__global__ void k_prep(const int* __restrict__ toks, int* __restrict__ meta) {
    __shared__ int st[B_DIM];
    int tid = threadIdx.x;
    if (tid < B_DIM) st[tid] = toks[tid];
    __syncthreads();
    if (tid == 0) {
        int ut[B_DIM];
        int inv[B_DIM];
        int ucount = 0;
        for (int b = 0; b < B_DIM; ++b) {
            int t = st[b];
            int slot = -1;
            for (int j = 0; j < ucount; ++j)
                if (ut[j] == t) { slot = j; break; }
            if (slot < 0) { slot = ucount; ut[ucount++] = t; }
            inv[b] = slot;
        }
        meta[0] = ucount;
        for (int b = 0; b < B_DIM; ++b) meta[1 + b] = inv[b];
        for (int j = 0; j < B_DIM; ++j) meta[65 + j] = (j < ucount) ? ut[j] : 0;
    }
}

// ------------------------------------------------- embed LN + h = relu(ln @ W1^T + b1)
__global__ __launch_bounds__(256) void k_gen_h(
        const float* __restrict__ embed_table, const float* __restrict__ g,
        const float* __restrict__ bb, const float* __restrict__ W1,
        const float* __restrict__ b1, const int* __restrict__ meta,
        float* __restrict__ h) {
    int u = blockIdx.x;
    int ucount = meta[0];
    int tid = threadIdx.x;
    if (u >= ucount) {
        h[(size_t)u * E_DIM + tid] = 0.0f;
        h[(size_t)u * E_DIM + tid + 256] = 0.0f;
        return;
    }
    int tok = meta[65 + u];
    const float* row = embed_table + (size_t)tok * E_DIM;
    float x0 = row[tid], x1 = row[tid + 256];
    float s = x0 + x1, sq = x0 * x0 + x1 * x1;
    #pragma unroll
    for (int m = 1; m < 64; m <<= 1) { s += __shfl_xor(s, m, 64); sq += __shfl_xor(sq, m, 64); }
    __shared__ float red[4][2];
    int wv = tid >> 6, ln = tid & 63;
    if (ln == 0) { red[wv][0] = s; red[wv][1] = sq; }
    __syncthreads();
    s = red[0][0] + red[1][0] + red[2][0] + red[3][0];
    sq = red[0][1] + red[1][1] + red[2][1] + red[3][1];
    float mu = s * (1.0f / E_DIM);
    float rs = rsqrtf(sq * (1.0f / E_DIM) - mu * mu + LN_EPS);
    __shared__ float lnv[E_DIM];
    lnv[tid] = (x0 - mu) * rs * g[tid] + bb[tid];
    lnv[tid + 256] = (x1 - mu) * rs * g[tid + 256] + bb[tid + 256];
    __syncthreads();
    #pragma unroll
    for (int cc = 0; cc < 2; ++cc) {
        int col = tid + cc * 256;
        const float* wrow = W1 + (size_t)col * E_DIM;
        float acc = b1[col];
        for (int k = 0; k < E_DIM; k += 4) {
            float4 w = *(const float4*)(wrow + k);
            float4 l4 = *(const float4*)(&lnv[k]);
            acc += w.x * l4.x + w.y * l4.y + w.z * l4.z + w.w * l4.w;
        }
        h[(size_t)u * E_DIM + col] = fmaxf(acc, 0.0f);
    }
}

// ------------------------------------------------- feat LN -> f16, layout [b][T][C]
__global__ __launch_bounds__(256) void k_featn(
        const float* __restrict__ feat, const float* __restrict__ g,
        const float* __restrict__ bb, _Float16* __restrict__ featn) {
    int r = blockIdx.x;              // r = t*B + b (source row, LN over contiguous C)
    int t = r / B_DIM, b = r % B_DIM;
    const float* x = feat + (size_t)r * C_DIM;
    int tid = threadIdx.x;
    float4 v = *(const float4*)(x + tid * 4);
    float s = v.x + v.y + v.z + v.w;
    float sq = v.x * v.x + v.y * v.y + v.z * v.z + v.w * v.w;
    #pragma unroll
    for (int m = 1; m < 64; m <<= 1) { s += __shfl_xor(s, m, 64); sq += __shfl_xor(sq, m, 64); }
    __shared__ float red[4][2];
    int wv = tid >> 6, ln = tid & 63;
    if (ln == 0) { red[wv][0] = s; red[wv][1] = sq; }
    __syncthreads();
    s = red[0][0] + red[1][0] + red[2][0] + red[3][0];
    sq = red[0][1] + red[1][1] + red[2][1] + red[3][1];
    float mu = s * (1.0f / C_DIM);
    float rs = rsqrtf(sq * (1.0f / C_DIM) - mu * mu + LN_EPS);
    float4 gv = *(const float4*)(g + tid * 4);
    float4 bv = *(const float4*)(bb + tid * 4);
    half4v o;
    o[0] = (_Float16)((v.x - mu) * rs * gv.x + bv.x);
    o[1] = (_Float16)((v.y - mu) * rs * gv.y + bv.y);
    o[2] = (_Float16)((v.z - mu) * rs * gv.z + bv.z);
    o[3] = (_Float16)((v.w - mu) * rs * gv.w + bv.w);
    *(half4v*)(featn + ((size_t)b * T_DIM + t) * C_DIM + tid * 4) = o;
}

// ------------------------------------------------- Wmap: global_load_lds + counted vmcnt (T3/T4)
// r9 probe: pure-HBM read = 5.57 TB/s; wmap variants pinned at 4.0-4.3 because every beat
// drained vmcnt to 0 (reg write-late needs loads complete; __syncthreads emits vmcnt(0)).
// This version NEVER drains in steady state: DMA staging (global_load_lds, 16B) into a
// tri-buffered 32KB f32 tile, 2-deep prefetch, raw s_barrier + explicit counted waits:
// steady beat n: stage t_{n+2}; WAITV(16) [wave0 18: +its b2 load & store, in-order
// retirement per m135]; barrier; compute (ds_read+cvt+MFMA, K-split over 4 waves);
// red partials; lgkmcnt(0); barrier; wave0 reduce+bias+relu+store. vmcnt hits 0 only at
// the last 2 beats. LDS swizzle is both-sides (rule 21): lds(row,chunk) holds global
// chunk^((row&7)<<1); read applies same XOR (verified element-wise; 4-way residual
// conflict, off critical path). Grid MUST be 256 (NT=32768=256x128, 1 block/CU, 116KB LDS).
__device__ __forceinline__ void stage_tile(const float* __restrict__ W2,
                                           float (*buf)[16][512], int bi, long tt,
                                           int wid, int lane) {
    const float* g = W2 + (size_t)tt * 8192;
    #pragma unroll
    for (int j = 0; j < 8; ++j) {
        int row = 4 * wid + (j >> 1);              // wave-uniform
        int chl = (j & 1) * 64 + lane;             // lds 16B-chunk within row
        int chg = chl ^ ((row & 7) << 1);          // pre-swizzled global chunk
        const float* src = g + (size_t)row * 512 + (size_t)chg * 4;
        char* dst = (char*)(&buf[bi][0][0]) + row * 2048 + (j & 1) * 1024;  // wave-uniform
        __builtin_amdgcn_global_load_lds((const __attribute__((address_space(1))) void*)src,
                                         (__attribute__((address_space(3))) void*)dst,
                                         16, 0, 0);
    }
}

__global__ __launch_bounds__(256) void k_wmap(
        const float* __restrict__ W2, const float* __restrict__ b2,
        const float* __restrict__ h, const int* __restrict__ meta,
        _Float16* __restrict__ wmap, int cap) {
    int ucount = meta[0];
    if (ucount > cap) ucount = cap;
    int tid = threadIdx.x;
    int lane = tid & 63;
    int wid = tid >> 6;                 // wave = K-quarter owner
    int fr = lane & 15, fq = lane >> 4;

    __shared__ float buf[3][16][512];        // 3 x 32 KB f32 tiles (DMA dest, swizzled chunks)
    __shared__ _Float16 hseg[16][64][8];     // B-fragments, 16 KB
    __shared__ float red[4][64][4];          // K-split partials, 4 KB

    const int NB = 128;                      // tiles per block (grid 256 x 128 = 32768 = CE/16)
    long tb = (long)blockIdx.x * NB;

    for (int sg = 0; sg < ucount; sg += 16) {
        // issue first two tiles' DMA before hseg fill (overlaps flight with VALU work)
        stage_tile(W2, buf, 0, tb + 0, wid, lane);
        stage_tile(W2, buf, 1, tb + 1, wid, lane);
        {   // populate hseg: thread t -> h-row (t&15), k-chunk (t>>4)*32..+32
            int pfr = tid & 15, pks = tid >> 4;
            const float* hp = h + (size_t)(sg + pfr) * E_DIM + pks * 32;
            #pragma unroll
            for (int pq = 0; pq < 4; ++pq) {
                float4 a = *(const float4*)(hp + pq * 8);
                float4 b = *(const float4*)(hp + pq * 8 + 4);
                half8 v;
                v[0] = (_Float16)a.x; v[1] = (_Float16)a.y;
                v[2] = (_Float16)a.z; v[3] = (_Float16)a.w;
                v[4] = (_Float16)b.x; v[5] = (_Float16)b.y;
                v[6] = (_Float16)b.z; v[7] = (_Float16)b.w;
                *(half8*)(&hseg[pks][pq * 16 + pfr][0]) = v;
            }
        }
        int nu = ucount - sg; if (nu > 16) nu = 16;
        __syncthreads();   // one-time full drain; beats 0-1 trivially satisfied after this

        int bi = 0;
        for (int n = 0; n < NB; ++n) {
            if (n + 2 < NB) {
                int bn = bi + 2; if (bn >= 3) bn -= 3;
                stage_tile(W2, buf, bn, tb + n + 2, wid, lane);
            }
            // counted waits: need tile n's 8 DMA loads retired; keep the rest in flight.
            if (n <= NB - 3) {
                if (wid == 0) { WAITV(18); } else { WAITV(16); }
            } else if (n == NB - 2) {
                if (wid == 0) { WAITV(10); } else { WAITV(8); }
            } else {
                WAITV(0);
            }
            __builtin_amdgcn_s_barrier();

            // compute K-quarter wid of tile n from buf[bi]
            f32x4 acc = {};
            const char* bp = (const char*)(&buf[bi][0][0]);
            #pragma unroll
            for (int ks = 0; ks < 4; ++ks) {
                int c0 = wid * 32 + ks * 8 + fq * 2;          // even 16B-chunk index
                int cp = c0 ^ ((fr & 7) << 1);                // matches stage swizzle
                float4 x0 = *(const float4*)(bp + fr * 2048 + cp * 16);
                float4 x1 = *(const float4*)(bp + fr * 2048 + cp * 16 + 16);
                half8 af;
                af[0] = (_Float16)x0.x; af[1] = (_Float16)x0.y;
                af[2] = (_Float16)x0.z; af[3] = (_Float16)x0.w;
                af[4] = (_Float16)x1.x; af[5] = (_Float16)x1.y;
                af[6] = (_Float16)x1.z; af[7] = (_Float16)x1.w;
                half8 bf = *(const half8*)(&hseg[wid * 4 + ks][lane][0]);
                acc = __builtin_amdgcn_mfma_f32_16x16x32_f16(af, bf, acc, 0, 0, 0);
            }
            *(f32x4*)(&red[wid][lane][0]) = acc;
            WAITL();                       // red visible (does NOT touch vmcnt)
            __builtin_amdgcn_s_barrier();

            if (wid == 0) {                // reduce K-split, bias+relu, store (as r8, verified)
                f32x4 s0 = *(const f32x4*)(&red[0][lane][0]);
                f32x4 s1 = *(const f32x4*)(&red[1][lane][0]);
                f32x4 s2 = *(const f32x4*)(&red[2][lane][0]);
                f32x4 s3 = *(const f32x4*)(&red[3][lane][0]);
                f32x4 s = (s0 + s1) + (s2 + s3);
                if (fr < nu) {
                    long i0 = (tb + n) * 16;
                    float4 bv = *(const float4*)(b2 + i0 + fq * 4);
                    half4v o;
                    o[0] = (_Float16)fmaxf(s[0] + bv.x, 0.0f);
                    o[1] = (_Float16)fmaxf(s[1] + bv.y, 0.0f);
                    o[2] = (_Float16)fmaxf(s[2] + bv.z, 0.0f);
                    o[3] = (_Float16)fmaxf(s[3] + bv.w, 0.0f);
                    *(half4v*)(wmap + (size_t)(sg + fr) * CE + i0 + fq * 4) = o;
                }
            }
            ++bi; if (bi >= 3) bi = 0;
        }
        __syncthreads();   // hygiene drain between sg groups (runs once: ucount <= 8)
    }
}

// ------------------------------------------------- out = featn @ Wmap[inv[b]]^T (per batch)
__global__ __launch_bounds__(256) void k_einsum(
        const _Float16* __restrict__ featn, const _Float16* __restrict__ wmap,
        const int* __restrict__ meta, float* __restrict__ out, int cap) {
    int b = blockIdx.z;
    int s = meta[1 + b];
    if (s >= cap) s = cap - 1;
    int M0 = blockIdx.y * 128;
    int N0 = blockIdx.x * 128;
    __shared__ _Float16 As[4][128][8];
    __shared__ _Float16 Bs[4][128][8];
    const _Float16* Abase = featn + (size_t)b * T_DIM * C_DIM;
    const _Float16* Bbase = wmap + (size_t)s * CE + (size_t)N0 * C_DIM;
    int tid = threadIdx.x;
    int lane = tid & 63, wv = tid >> 6;
    int wrow = (wv >> 1) * 64, wcol = (wv & 1) * 64;
    int fr = lane & 15, fq = lane >> 4;
    f32x4 acc[4][4] = {};
    for (int kt = 0; kt < C_DIM / 32; ++kt) {
        int k0 = kt * 32;
        #pragma unroll
        for (int hh = 0; hh < 2; ++hh) {
            int id = tid + hh * 256;
            int r = id >> 2, q = id & 3;
            int t = M0 + r;
            uint4 av = make_uint4(0u, 0u, 0u, 0u);
            if (t < T_DIM) av = *(const uint4*)(Abase + (size_t)t * C_DIM + k0 + q * 8);
            *(uint4*)(&As[q][r][0]) = av;
            uint4 bvv = *(const uint4*)(Bbase + (size_t)r * C_DIM + k0 + q * 8);
            *(uint4*)(&Bs[q][r][0]) = bvv;
        }
        __syncthreads();
        half8 af[4], bf[4];
        #pragma unroll
        for (int mi = 0; mi < 4; ++mi) af[mi] = *(const half8*)(&As[fq][wrow + mi * 16 + fr][0]);
        #pragma unroll
        for (int ni = 0; ni < 4; ++ni) bf[ni] = *(const half8*)(&Bs[fq][wcol + ni * 16 + fr][0]);
        #pragma unroll
        for (int mi = 0; mi < 4; ++mi) {
            #pragma unroll
            for (int ni = 0; ni < 4; ++ni) {
                acc[mi][ni] = __builtin_amdgcn_mfma_f32_16x16x32_f16(af[mi], bf[ni], acc[mi][ni], 0, 0, 0);
            }
        }
        __syncthreads();
    }
    #pragma unroll
    for (int mi = 0; mi < 4; ++mi) {
        #pragma unroll
        for (int ni = 0; ni < 4; ++ni) {
            #pragma unroll
            for (int j = 0; j < 4; ++j) {
                int t = M0 + wrow + mi * 16 + fq * 4 + j;
                int e = N0 + wcol + ni * 16 + fr;
                if (t < T_DIM)
                    out[((size_t)t * B_DIM + b) * E_DIM + e] = acc[mi][ni][j];
            }
        }
    }
}

extern "C" void kernel_launch(void* const* d_in, const int* in_sizes, int n_in,
                              void* d_out, int out_size, void* d_ws, size_t ws_size,
                              hipStream_t stream) {
    const float* feat = (const float*)d_in[0];
    const int* toks = (const int*)d_in[1];
    const float* embed_table = (const float*)d_in[2];
    const float* eg = (const float*)d_in[3];
    const float* ebv = (const float*)d_in[4];
    const float* fg = (const float*)d_in[5];
    const float* fb = (const float*)d_in[6];
    const float* W1 = (const float*)d_in[7];
    const float* b1 = (const float*)d_in[8];
    const float* W2 = (const float*)d_in[9];
    const float* b2 = (const float*)d_in[10];
    float* out = (float*)d_out;

    char* ws = (char*)d_ws;
    int* meta = (int*)(ws + META_OFF);
    float* h = (float*)(ws + H_OFF);
    _Float16* featn = (_Float16*)(ws + FEATN_OFF);
    _Float16* wmap = (_Float16*)(ws + WMAP_OFF);

    long cap = 1;
    if (ws_size > (size_t)WMAP_OFF)
        cap = (long)((ws_size - (size_t)WMAP_OFF) / ((size_t)CE * 2));
    if (cap > 64) cap = 64;
    if (cap < 1) cap = 1;

    hipLaunchKernelGGL(k_prep, dim3(1), dim3(64), 0, stream, toks, meta);
    hipLaunchKernelGGL(k_gen_h, dim3(64), dim3(256), 0, stream,
                       embed_table, eg, ebv, W1, b1, meta, h);
    hipLaunchKernelGGL(k_featn, dim3(T_DIM * B_DIM), dim3(256), 0, stream,
                       feat, fg, fb, featn);
    hipLaunchKernelGGL(k_wmap, dim3(256), dim3(256), 0, stream,
                       W2, b2, h, meta, wmap, (int)cap);   // grid MUST be 256 (NB=128)
    hipLaunchKernelGGL(k_einsum, dim3(4, 2, 64), dim3(256), 0, stream,
                       featn, wmap, meta, out, (int)cap);
}

// Round 11
// 316.772 us; speedup vs baseline: 2.8751x; 1.2810x over previous
//
#include <hip/hip_runtime.h>
#include <hip/hip_bf16.h>
#include <hip/hip_fp16.h>

typedef _Float16 half8 __attribute__((ext_vector_type(8)));
typedef _Float16 half4v __attribute__((ext_vector_type(4)));
typedef float f32x4 __attribute__((ext_vector_type(4)));

#define T_DIM 196
#define B_DIM 64
#define C_DIM 1024
#define E_DIM 512
#define CE (C_DIM * E_DIM)   // 524288
#define LN_EPS 1e-5f

// ws layout (bytes)
#define META_OFF 0            // ints: [0]=ucount, [1..64]=inv[b], [65..128]=utoks
#define H_OFF 4096            // 64 * 512 f32 = 131072
#define FEATN_OFF 135168      // T*B*C f16 = 25690112 (layout [b][T][C])
#define WMAP_OFF 25825280     // cap * CE f16 (1 MiB per slot)

// ---------------------------------------------------------------- dedupe
__global__ void k_prep(const int* __restrict__ toks, int* __restrict__ meta) {
    __shared__ int st[B_DIM];
    int tid = threadIdx.x;
    if (tid < B_DIM) st[tid] = toks[tid];
    __syncthreads();
    if (tid == 0) {
        int ut[B_DIM];
        int inv[B_DIM];
        int ucount = 0;
        for (int b = 0; b < B_DIM; ++b) {
            int t = st[b];
            int slot = -1;
            for (int j = 0; j < ucount; ++j)
                if (ut[j] == t) { slot = j; break; }
            if (slot < 0) { slot = ucount; ut[ucount++] = t; }
            inv[b] = slot;
        }
        meta[0] = ucount;
        for (int b = 0; b < B_DIM; ++b) meta[1 + b] = inv[b];
        for (int j = 0; j < B_DIM; ++j) meta[65 + j] = (j < ucount) ? ut[j] : 0;
    }
}

// ------------------------------------------------- embed LN + h = relu(ln @ W1^T + b1)
__global__ __launch_bounds__(256) void k_gen_h(
        const float* __restrict__ embed_table, const float* __restrict__ g,
        const float* __restrict__ bb, const float* __restrict__ W1,
        const float* __restrict__ b1, const int* __restrict__ meta,
        float* __restrict__ h) {
    int u = blockIdx.x;
    int ucount = meta[0];
    int tid = threadIdx.x;
    if (u >= ucount) {
        h[(size_t)u * E_DIM + tid] = 0.0f;
        h[(size_t)u * E_DIM + tid + 256] = 0.0f;
        return;
    }
    int tok = meta[65 + u];
    const float* row = embed_table + (size_t)tok * E_DIM;
    float x0 = row[tid], x1 = row[tid + 256];
    float s = x0 + x1, sq = x0 * x0 + x1 * x1;
    #pragma unroll
    for (int m = 1; m < 64; m <<= 1) { s += __shfl_xor(s, m, 64); sq += __shfl_xor(sq, m, 64); }
    __shared__ float red[4][2];
    int wv = tid >> 6, ln = tid & 63;
    if (ln == 0) { red[wv][0] = s; red[wv][1] = sq; }
    __syncthreads();
    s = red[0][0] + red[1][0] + red[2][0] + red[3][0];
    sq = red[0][1] + red[1][1] + red[2][1] + red[3][1];
    float mu = s * (1.0f / E_DIM);
    float rs = rsqrtf(sq * (1.0f / E_DIM) - mu * mu + LN_EPS);
    __shared__ float lnv[E_DIM];
    lnv[tid] = (x0 - mu) * rs * g[tid] + bb[tid];
    lnv[tid + 256] = (x1 - mu) * rs * g[tid + 256] + bb[tid + 256];
    __syncthreads();
    #pragma unroll
    for (int cc = 0; cc < 2; ++cc) {
        int col = tid + cc * 256;
        const float* wrow = W1 + (size_t)col * E_DIM;
        float acc = b1[col];
        for (int k = 0; k < E_DIM; k += 4) {
            float4 w = *(const float4*)(wrow + k);
            float4 l4 = *(const float4*)(&lnv[k]);
            acc += w.x * l4.x + w.y * l4.y + w.z * l4.z + w.w * l4.w;
        }
        h[(size_t)u * E_DIM + col] = fmaxf(acc, 0.0f);
    }
}

// ------------------------------------------------- feat LN -> f16, layout [b][T][C]
__global__ __launch_bounds__(256) void k_featn(
        const float* __restrict__ feat, const float* __restrict__ g,
        const float* __restrict__ bb, _Float16* __restrict__ featn) {
    int r = blockIdx.x;              // r = t*B + b (source row, LN over contiguous C)
    int t = r / B_DIM, b = r % B_DIM;
    const float* x = feat + (size_t)r * C_DIM;
    int tid = threadIdx.x;
    float4 v = *(const float4*)(x + tid * 4);
    float s = v.x + v.y + v.z + v.w;
    float sq = v.x * v.x + v.y * v.y + v.z * v.z + v.w * v.w;
    #pragma unroll
    for (int m = 1; m < 64; m <<= 1) { s += __shfl_xor(s, m, 64); sq += __shfl_xor(sq, m, 64); }
    __shared__ float red[4][2];
    int wv = tid >> 6, ln = tid & 63;
    if (ln == 0) { red[wv][0] = s; red[wv][1] = sq; }
    __syncthreads();
    s = red[0][0] + red[1][0] + red[2][0] + red[3][0];
    sq = red[0][1] + red[1][1] + red[2][1] + red[3][1];
    float mu = s * (1.0f / C_DIM);
    float rs = rsqrtf(sq * (1.0f / C_DIM) - mu * mu + LN_EPS);
    float4 gv = *(const float4*)(g + tid * 4);
    float4 bv = *(const float4*)(bb + tid * 4);
    half4v o;
    o[0] = (_Float16)((v.x - mu) * rs * gv.x + bv.x);
    o[1] = (_Float16)((v.y - mu) * rs * gv.y + bv.y);
    o[2] = (_Float16)((v.z - mu) * rs * gv.z + bv.z);
    o[3] = (_Float16)((v.w - mu) * rs * gv.w + bv.w);
    *(half4v*)(featn + ((size_t)b * T_DIM + t) * C_DIM + tid * 4) = o;
}

// ------------------------------------------------- Wmap via MFMA (round-6 verbatim: best measured, ~265us)
__global__ __launch_bounds__(256) void k_wmap(
        const float* __restrict__ W2, const float* __restrict__ b2,
        const float* __restrict__ h, const int* __restrict__ meta,
        _Float16* __restrict__ wmap, int cap) {
    int ucount = meta[0];
    if (ucount > cap) ucount = cap;
    int tid = threadIdx.x;
    int lane = tid & 63;
    int wid = tid >> 6;
    int fr = lane & 15, fq = lane >> 4;
    int l5 = lane >> 5;
    int c31 = lane & 31;
    __shared__ float sbuf[4][2][16][128];   // [wave][buf][row][f32] = 64 KB
    __shared__ _Float16 hseg[16][64][8];    // B-fragments, 16 KB

    long nwaves = (long)gridDim.x * 4;
    long gw = (long)blockIdx.x * 4 + wid;
    const long NT = CE / 16;

    for (int sg = 0; sg < ucount; sg += 16) {
        __syncthreads();
        {
            int pfr = tid & 15, pks = tid >> 4;
            const float* hp = h + (size_t)(sg + pfr) * E_DIM + pks * 32;
            #pragma unroll
            for (int pq = 0; pq < 4; ++pq) {
                float4 a = *(const float4*)(hp + pq * 8);
                float4 b = *(const float4*)(hp + pq * 8 + 4);
                half8 v;
                v[0] = (_Float16)a.x; v[1] = (_Float16)a.y;
                v[2] = (_Float16)a.z; v[3] = (_Float16)a.w;
                v[4] = (_Float16)b.x; v[5] = (_Float16)b.y;
                v[6] = (_Float16)b.z; v[7] = (_Float16)b.w;
                *(half8*)(&hseg[pks][pq * 16 + pfr][0]) = v;
            }
        }
        __syncthreads();
        int nu = ucount - sg;

        long ntiles = (gw < NT) ? ((NT - gw + nwaves - 1) / nwaves) : 0;
        if (ntiles > 0) {
            long nq = ntiles * 4;
            {
                long i0 = gw * 16;
                #pragma unroll
                for (int s = 0; s < 8; ++s) {
                    int row = 2 * s + l5;
                    float4 rv = *(const float4*)(W2 + (size_t)(i0 + row) * E_DIM + c31 * 4);
                    *(float4*)(&sbuf[wid][0][row][(c31 ^ (row & 7)) * 4]) = rv;
                }
            }
            f32x4 acc = {};
            for (long qq = 0; qq < nq; ++qq) {
                int cur = (int)(qq & 1);
                bool have = (qq + 1 < nq);
                float4 rr0, rr1, rr2, rr3, rr4, rr5, rr6, rr7;
                if (have) {
                    long g2 = gw + ((qq + 1) >> 2) * nwaves;
                    int qn = (int)((qq + 1) & 3);
                    const float* base = W2 + (size_t)(g2 * 16) * E_DIM + qn * 128 + c31 * 4;
                    rr0 = *(const float4*)(base + (size_t)(0  + l5) * E_DIM);
                    rr1 = *(const float4*)(base + (size_t)(2  + l5) * E_DIM);
                    rr2 = *(const float4*)(base + (size_t)(4  + l5) * E_DIM);
                    rr3 = *(const float4*)(base + (size_t)(6  + l5) * E_DIM);
                    rr4 = *(const float4*)(base + (size_t)(8  + l5) * E_DIM);
                    rr5 = *(const float4*)(base + (size_t)(10 + l5) * E_DIM);
                    rr6 = *(const float4*)(base + (size_t)(12 + l5) * E_DIM);
                    rr7 = *(const float4*)(base + (size_t)(14 + l5) * E_DIM);
                    __builtin_amdgcn_sched_barrier(0);
                }
                int q = (int)(qq & 3);
                #pragma unroll
                for (int ks = 0; ks < 4; ++ks) {
                    int c0 = ks * 8 + fq * 2;
                    float4 x0 = *(const float4*)(&sbuf[wid][cur][fr][(c0 ^ (fr & 7)) * 4]);
                    float4 x1 = *(const float4*)(&sbuf[wid][cur][fr][((c0 + 1) ^ (fr & 7)) * 4]);
                    half8 af;
                    af[0] = (_Float16)x0.x; af[1] = (_Float16)x0.y;
                    af[2] = (_Float16)x0.z; af[3] = (_Float16)x0.w;
                    af[4] = (_Float16)x1.x; af[5] = (_Float16)x1.y;
                    af[6] = (_Float16)x1.z; af[7] = (_Float16)x1.w;
                    half8 bf = *(const half8*)(&hseg[q * 4 + ks][lane][0]);
                    acc = __builtin_amdgcn_mfma_f32_16x16x32_f16(af, bf, acc, 0, 0, 0);
                }
                if (q == 3) {
                    long i0 = (gw + (qq >> 2) * nwaves) * 16;
                    if (fr < nu) {
                        float4 bv = *(const float4*)(b2 + i0 + fq * 4);
                        half4v o;
                        o[0] = (_Float16)fmaxf(acc[0] + bv.x, 0.0f);
                        o[1] = (_Float16)fmaxf(acc[1] + bv.y, 0.0f);
                        o[2] = (_Float16)fmaxf(acc[2] + bv.z, 0.0f);
                        o[3] = (_Float16)fmaxf(acc[3] + bv.w, 0.0f);
                        *(half4v*)(wmap + (size_t)(sg + fr) * CE + i0 + fq * 4) = o;
                    }
                    acc[0] = 0.0f; acc[1] = 0.0f; acc[2] = 0.0f; acc[3] = 0.0f;
                }
                if (have) {
                    int nb = cur ^ 1;
                    *(float4*)(&sbuf[wid][nb][0  + l5][(c31 ^ ((0  + l5) & 7)) * 4]) = rr0;
                    *(float4*)(&sbuf[wid][nb][2  + l5][(c31 ^ ((2  + l5) & 7)) * 4]) = rr1;
                    *(float4*)(&sbuf[wid][nb][4  + l5][(c31 ^ ((4  + l5) & 7)) * 4]) = rr2;
                    *(float4*)(&sbuf[wid][nb][6  + l5][(c31 ^ ((6  + l5) & 7)) * 4]) = rr3;
                    *(float4*)(&sbuf[wid][nb][8  + l5][(c31 ^ ((8  + l5) & 7)) * 4]) = rr4;
                    *(float4*)(&sbuf[wid][nb][10 + l5][(c31 ^ ((10 + l5) & 7)) * 4]) = rr5;
                    *(float4*)(&sbuf[wid][nb][12 + l5][(c31 ^ ((12 + l5) & 7)) * 4]) = rr6;
                    *(float4*)(&sbuf[wid][nb][14 + l5][(c31 ^ ((14 + l5) & 7)) * 4]) = rr7;
                }
            }
        }
    }
}

// ------------------------------------------------- out = featn @ Wmap[inv[b]]^T (per batch)
// r11 restructure (einsum is latency/occupancy-bound; inputs L2/L3-resident):
// M-tile 64 (grid 4x4x64 = 1024 blocks -> 4-6 blocks/CU, 16-24 waves/CU vs old 8),
// BK=64 (32 barriers vs 64), padded-row LDS As[8][65][8]/Bs[8][129][8]: staging
// ds_writes conflict-free (bank 4q+4r distinct over the 8 lanes sharing r), fragment
// ds_read_b128 2-way (free), 16B alignment preserved. Fragment mapping and per-element
// k-ascending accumulation order unchanged -> bit-identical output to r6/r8 einsum.
__global__ __launch_bounds__(256) void k_einsum(
        const _Float16* __restrict__ featn, const _Float16* __restrict__ wmap,
        const int* __restrict__ meta, float* __restrict__ out, int cap) {
    int b = blockIdx.z;
    int s = meta[1 + b];
    if (s >= cap) s = cap - 1;
    int M0 = blockIdx.y * 64;
    int N0 = blockIdx.x * 128;
    __shared__ _Float16 As[8][65][8];    // [kchunk][row(t)][8 k], row-padded
    __shared__ _Float16 Bs[8][129][8];   // [kchunk][row(e)][8 k], row-padded
    const _Float16* Abase = featn + (size_t)b * T_DIM * C_DIM;
    const _Float16* Bbase = wmap + (size_t)s * CE + (size_t)N0 * C_DIM;
    int tid = threadIdx.x;
    int lane = tid & 63, wv = tid >> 6;
    int wrow = (wv >> 1) * 32, wcol = (wv & 1) * 64;
    int fr = lane & 15, fq = lane >> 4;
    f32x4 acc[2][4] = {};
    for (int kt = 0; kt < C_DIM / 64; ++kt) {
        int k0 = kt * 64;
        // stage As: 64 rows x 8 chunks = 512 x 16B units
        #pragma unroll
        for (int hh = 0; hh < 2; ++hh) {
            int id2 = tid + hh * 256;
            int r = id2 >> 3, q = id2 & 7;
            int t = M0 + r;
            uint4 av = make_uint4(0u, 0u, 0u, 0u);
            if (t < T_DIM) av = *(const uint4*)(Abase + (size_t)t * C_DIM + k0 + q * 8);
            *(uint4*)(&As[q][r][0]) = av;
        }
        // stage Bs: 128 rows x 8 chunks = 1024 x 16B units
        #pragma unroll
        for (int hh = 0; hh < 4; ++hh) {
            int id2 = tid + hh * 256;
            int r = id2 >> 3, q = id2 & 7;
            uint4 bvv = *(const uint4*)(Bbase + (size_t)r * C_DIM + k0 + q * 8);
            *(uint4*)(&Bs[q][r][0]) = bvv;
        }
        __syncthreads();
        #pragma unroll
        for (int ks = 0; ks < 2; ++ks) {
            half8 af[2], bf[4];
            #pragma unroll
            for (int mi = 0; mi < 2; ++mi)
                af[mi] = *(const half8*)(&As[ks * 4 + fq][wrow + mi * 16 + fr][0]);
            #pragma unroll
            for (int ni = 0; ni < 4; ++ni)
                bf[ni] = *(const half8*)(&Bs[ks * 4 + fq][wcol + ni * 16 + fr][0]);
            #pragma unroll
            for (int mi = 0; mi < 2; ++mi) {
                #pragma unroll
                for (int ni = 0; ni < 4; ++ni) {
                    acc[mi][ni] = __builtin_amdgcn_mfma_f32_16x16x32_f16(af[mi], bf[ni], acc[mi][ni], 0, 0, 0);
                }
            }
        }
        __syncthreads();
    }
    #pragma unroll
    for (int mi = 0; mi < 2; ++mi) {
        #pragma unroll
        for (int ni = 0; ni < 4; ++ni) {
            #pragma unroll
            for (int j = 0; j < 4; ++j) {
                int t = M0 + wrow + mi * 16 + fq * 4 + j;
                int e = N0 + wcol + ni * 16 + fr;
                if (t < T_DIM)
                    out[((size_t)t * B_DIM + b) * E_DIM + e] = acc[mi][ni][j];
            }
        }
    }
}

extern "C" void kernel_launch(void* const* d_in, const int* in_sizes, int n_in,
                              void* d_out, int out_size, void* d_ws, size_t ws_size,
                              hipStream_t stream) {
    const float* feat = (const float*)d_in[0];
    const int* toks = (const int*)d_in[1];
    const float* embed_table = (const float*)d_in[2];
    const float* eg = (const float*)d_in[3];
    const float* ebv = (const float*)d_in[4];
    const float* fg = (const float*)d_in[5];
    const float* fb = (const float*)d_in[6];
    const float* W1 = (const float*)d_in[7];
    const float* b1 = (const float*)d_in[8];
    const float* W2 = (const float*)d_in[9];
    const float* b2 = (const float*)d_in[10];
    float* out = (float*)d_out;

    char* ws = (char*)d_ws;
    int* meta = (int*)(ws + META_OFF);
    float* h = (float*)(ws + H_OFF);
    _Float16* featn = (_Float16*)(ws + FEATN_OFF);
    _Float16* wmap = (_Float16*)(ws + WMAP_OFF);

    long cap = 1;
    if (ws_size > (size_t)WMAP_OFF)
        cap = (long)((ws_size - (size_t)WMAP_OFF) / ((size_t)CE * 2));
    if (cap > 64) cap = 64;
    if (cap < 1) cap = 1;

    hipLaunchKernelGGL(k_prep, dim3(1), dim3(64), 0, stream, toks, meta);
    hipLaunchKernelGGL(k_gen_h, dim3(64), dim3(256), 0, stream,
                       embed_table, eg, ebv, W1, b1, meta, h);
    hipLaunchKernelGGL(k_featn, dim3(T_DIM * B_DIM), dim3(256), 0, stream,
                       feat, fg, fb, featn);
    hipLaunchKernelGGL(k_wmap, dim3(1024), dim3(256), 0, stream,
                       W2, b2, h, meta, wmap, (int)cap);
    hipLaunchKernelGGL(k_einsum, dim3(4, 4, 64), dim3(256), 0, stream,
                       featn, wmap, meta, out, (int)cap);
}